// Round 11
// baseline (31857.074 us; speedup 1.0000x reference)
//
#include <hip/hip_runtime.h>
#include <stdint.h>

#define TSTEPS 512

typedef __attribute__((ext_vector_type(8))) _Float16 half8;
typedef __attribute__((ext_vector_type(4))) _Float16 half4;
typedef __attribute__((ext_vector_type(4))) float f32x4;
typedef __attribute__((ext_vector_type(4))) float float4v;
typedef __attribute__((ext_vector_type(4))) int i32x4;
typedef unsigned long long u64;

static __device__ __forceinline__ float sigm(float x) { return 1.f / (1.f + __expf(-x)); }
static __device__ __forceinline__ float tanh_(float x) {
  x = fminf(15.f, fmaxf(-15.f, x));
  float e = __expf(-2.f * x);
  return (1.f - e) / (1.f + e);
}
static __device__ __forceinline__ half8 ld8(const _Float16* p) { return *(const half8*)p; }
static __device__ __forceinline__ f32x4 MFMA(half8 a, half8 b, f32x4 c) {
  return __builtin_amdgcn_mfma_f32_16x16x32_f16(a, b, c, 0, 0, 0);
}

// ---- MALL primitives (agent scope; r4/r5/r10-proven) ----
static __device__ __forceinline__ unsigned aadd(unsigned* p) {
  return __hip_atomic_fetch_add(p, 1u, __ATOMIC_RELAXED, __HIP_MEMORY_SCOPE_AGENT);
}
static __device__ __forceinline__ unsigned ald(const unsigned* p) {
  return __hip_atomic_load(p, __ATOMIC_RELAXED, __HIP_MEMORY_SCOPE_AGENT);
}
static __device__ __forceinline__ void ast(unsigned* p, unsigned v) {
  __hip_atomic_store(p, v, __ATOMIC_RELAXED, __HIP_MEMORY_SCOPE_AGENT);
}
static __device__ __forceinline__ u64 ald64(const u64* p) {
  return __hip_atomic_load(p, __ATOMIC_RELAXED, __HIP_MEMORY_SCOPE_AGENT);
}
static __device__ __forceinline__ void ast64(u64* p, u64 v) {
  __hip_atomic_store(p, v, __ATOMIC_RELAXED, __HIP_MEMORY_SCOPE_AGENT);
}

// ---- sc0 (SE-scope) loads: bypass L1, read the local XCD L2. NO RMW (r10 lesson).
static __device__ __forceinline__ unsigned ld_sc0_u32(const unsigned* p) {
  unsigned v;
  asm volatile("global_load_dword %0, %1, off sc0\n\ts_waitcnt vmcnt(0)"
               : "=v"(v) : "v"(p) : "memory");
  return v;
}
static __device__ __forceinline__ void ld_fast_frag(const u64* p, i32x4* q) {
  asm volatile(
    "global_load_dwordx4 %0, %8, off sc0\n\t"
    "global_load_dwordx4 %1, %8, off offset:16 sc0\n\t"
    "global_load_dwordx4 %2, %8, off offset:128 sc0\n\t"
    "global_load_dwordx4 %3, %8, off offset:144 sc0\n\t"
    "global_load_dwordx4 %4, %8, off offset:256 sc0\n\t"
    "global_load_dwordx4 %5, %8, off offset:272 sc0\n\t"
    "global_load_dwordx4 %6, %8, off offset:384 sc0\n\t"
    "global_load_dwordx4 %7, %8, off offset:400 sc0\n\t"
    "s_waitcnt vmcnt(0)"
    : "=&v"(q[0]), "=&v"(q[1]), "=&v"(q[2]), "=&v"(q[3]),
      "=&v"(q[4]), "=&v"(q[5]), "=&v"(q[6]), "=&v"(q[7])
    : "v"(p) : "memory");
}

// ---------------- f32 -> f16 conversion ----------------
__global__ __launch_bounds__(256) void kconv(
    const float* __restrict__ xs, const float* __restrict__ wih,
    const float* __restrict__ wxh, const float* __restrict__ whhf,
    const float* __restrict__ wrf,
    _Float16* __restrict__ xs_h, _Float16* __restrict__ wcat,
    _Float16* __restrict__ whh, _Float16* __restrict__ wr) {
  const long n1 = 8388608, n2 = 1048576, n3 = 786432, n4 = 262144;
  const long total = n1 + n2 + n3 + n4;
  for (long i = (long)blockIdx.x * 256 + threadIdx.x; i < total; i += (long)gridDim.x * 256) {
    const float* s; _Float16* d;
    if (i < n1) { s = xs + i * 4; d = xs_h + i * 4; }
    else if (i < n1 + n2) {
      long e = (i - n1) * 4;
      s = (e < 3145728) ? (wih + e) : (wxh + (e - 3145728));
      d = wcat + e;
    } else if (i < n1 + n2 + n3) { long e = (i - n1 - n2) * 4; s = whhf + e; d = whh + e; }
    else { long e = (i - n1 - n2 - n3) * 4; s = wrf + e; d = wr + e; }
    float4v v = *(const float4v*)s;
    half4 o = { (_Float16)v.x, (_Float16)v.y, (_Float16)v.z, (_Float16)v.w };
    *(half4*)d = o;
  }
}

// ---------------- big input-side GEMM ----------------
__global__ __launch_bounds__(256) void kgemm(
    const _Float16* __restrict__ X, const _Float16* __restrict__ W,
    const float* __restrict__ b_ih, const float* __restrict__ b_xh,
    _Float16* __restrict__ C) {
  __shared__ _Float16 As[128 * 40], Bs[128 * 40];
  const int tid = threadIdx.x;
  const int lane = tid & 63;
  const int w = tid >> 6;
  const int wm = (w >> 1) * 64, wn = (w & 1) * 64;
  const int bn = blockIdx.x * 128;
  const int bm = blockIdx.y * 128;
  const int arow = tid >> 2;
  const int kk8 = (tid & 3) * 8;
  const int fr = lane & 15, fq = lane >> 4;
  const f32x4 zero = {0.f, 0.f, 0.f, 0.f};
  f32x4 acc[4][4];
  #pragma unroll
  for (int a = 0; a < 4; a++)
    #pragma unroll
    for (int b = 0; b < 4; b++) acc[a][b] = zero;
  for (int kt = 0; kt < 1024; kt += 32) {
    __syncthreads();
    #pragma unroll
    for (int j = 0; j < 2; j++) {
      int r = j * 64 + arow;
      *(half8*)(As + r * 40 + kk8) = ld8(X + (size_t)(bm + r) * 1024 + kt + kk8);
      *(half8*)(Bs + r * 40 + kk8) = ld8(W + (size_t)(bn + r) * 1024 + kt + kk8);
    }
    __syncthreads();
    half8 af[4], bfr[4];
    #pragma unroll
    for (int i = 0; i < 4; i++) {
      af[i]  = *(const half8*)(As + (wm + i * 16 + fr) * 40 + fq * 8);
      bfr[i] = *(const half8*)(Bs + (wn + i * 16 + fr) * 40 + fq * 8);
    }
    #pragma unroll
    for (int mi = 0; mi < 4; mi++)
      #pragma unroll
      for (int ni = 0; ni < 4; ni++)
        acc[mi][ni] = MFMA(af[mi], bfr[ni], acc[mi][ni]);
  }
  #pragma unroll
  for (int mi = 0; mi < 4; mi++)
    #pragma unroll
    for (int ni = 0; ni < 4; ni++) {
      int col = bn + wn + ni * 16 + fr;
      float bias = (col < 3072) ? b_ih[col] : b_xh[col - 3072];
      #pragma unroll
      for (int r = 0; r < 4; r++) {
        int row = bm + wm + mi * 16 + fq * 4 + r;
        C[(size_t)row * 4096 + col] = (_Float16)(acc[mi][ni][r] + bias);
      }
    }
}

// ---------------- persistent recurrent kernel ----------------
// 4 groups x 16 rows x 32 wgs x 512 thr. LOCAL: group == XCD; tagged msgs via
// plain stores -> local L2, sc0 reads; MALL dup buffer = liveness/correctness
// net (tag+epoch self-validating). FALLBACK: hint-gated MALL tag-poll (r7).
#define RP 20
#define TP (16 * RP)

// consume one 32-half fragment (16 tagged msgs). Returns 1 if escalated.
template<int LOCAL>
static __device__ __forceinline__ int consume_frag(
    const u64* fastb, const u64* dupb,
    const unsigned* hL, const unsigned* hD,
    unsigned tg, half8* av, int trust) {
  const int l = threadIdx.x & 31;
  if (LOCAL && trust) {
    // bounded sc0 hint poll (128B line)
    const unsigned* hp = hL + l;
    for (int it = 0; it < 384; ++it) {
      if (__all(ld_sc0_u32(hp) >= tg)) break;
      __builtin_amdgcn_s_sleep(1);
    }
    // bounded tagged fast reads from local L2
    for (int it = 0; it < 64; ++it) {
      i32x4 q[8];
      ld_fast_frag(fastb, q);
      bool ok = true;
      #pragma unroll
      for (int j = 0; j < 8; j++)
        ok &= ((unsigned)q[j].y == tg) & ((unsigned)q[j].w == tg);
      if (__all(ok)) {
        #pragma unroll
        for (int ks = 0; ks < 4; ks++) {
          i32x4 u = { q[2 * ks].x, q[2 * ks].z, q[2 * ks + 1].x, q[2 * ks + 1].z };
          av[ks] = __builtin_bit_cast(half8, u);
        }
        return 0;
      }
      __builtin_amdgcn_s_sleep(1);
    }
  }
  if (!LOCAL) {
    // fallback: hint-gated (avoids r6 congestion)
    const unsigned* hp = hD + l;
    while (!__all(ald(hp) >= tg))
      __builtin_amdgcn_s_sleep(1);
  }
  // MALL dup tag-poll (guaranteed live: producers always publish dups)
  for (;;) {
    u64 m[16];
    bool ok = true;
    #pragma unroll
    for (int ks = 0; ks < 4; ks++)
      #pragma unroll
      for (int qq = 0; qq < 4; qq++)
        m[ks * 4 + qq] = ald64(dupb + ks * 16 + qq);
    #pragma unroll
    for (int i = 0; i < 16; i++) ok &= ((unsigned)(m[i] >> 32) == tg);
    if (__all(ok)) {
      #pragma unroll
      for (int ks = 0; ks < 4; ks++) {
        i32x4 u = { (int)(unsigned)m[ks * 4 + 0], (int)(unsigned)m[ks * 4 + 1],
                    (int)(unsigned)m[ks * 4 + 2], (int)(unsigned)m[ks * 4 + 3] };
        av[ks] = __builtin_bit_cast(half8, u);
      }
      return 1;
    }
    __builtin_amdgcn_s_sleep(2);
  }
}

template<int LOCAL>
static __device__ void run_rec(
    int tid, int grp, int slot, unsigned ep16,
    const _Float16* __restrict__ xgh, const float* __restrict__ ms,
    const _Float16* __restrict__ whh, const _Float16* __restrict__ wr,
    const float* __restrict__ b_hh, const float* __restrict__ b_r,
    const float* __restrict__ h0,
    u64* __restrict__ hxF, u64* __restrict__ rhxF,
    u64* __restrict__ hxD, u64* __restrict__ rhxD,
    unsigned* __restrict__ hintL, unsigned* __restrict__ hintD,
    float* __restrict__ out, float* red) {
  const int lane = tid & 63, w = tid >> 6;
  const int fr = lane & 15, fq = lane >> 4;
  const int colbase = slot * 32;
  unsigned* hLA = hintL + (grp * 2 + 0) * 32;   // rh ready
  unsigned* hLB = hintL + (grp * 2 + 1) * 32;   // h ready
  unsigned* hDA = hintD + (grp * 2 + 0) * 32;
  unsigned* hDB = hintD + (grp * 2 + 1) * 32;

  // ---- weight fragments -> registers
  half8 wA[6][4], wB[2][4];
  #pragma unroll
  for (int nt = 0; nt < 6; nt++)
    #pragma unroll
    for (int ks = 0; ks < 4; ks++)
      wA[nt][ks] = ld8(whh + (size_t)((nt >> 1) * 1024 + colbase + (nt & 1) * 16 + fr) * 1024
                            + w * 128 + ks * 32 + fq * 8);
  #pragma unroll
  for (int nt = 0; nt < 2; nt++)
    #pragma unroll
    for (int ks = 0; ks < 4; ks++)
      wB[nt][ks] = ld8(wr + (size_t)(colbase + nt * 16 + fr) * 1024
                           + w * 128 + ks * 32 + fq * 8);

  // ---- every thread owns one (row b, col cc) cell
  const int b = tid >> 5, cc = tid & 31;
  const int gc = colbase + cc;
  const int gm = grp * 16 + b;
  const float bhr = b_hh[gc], bhz = b_hh[1024 + gc], bhe = b_hh[2048 + gc];
  const float brr = b_r[gc];
  float hreg = h0[(size_t)gm * 1024 + gc];

  // msg bases (u64/msg units; row stride 512 msgs)
  const size_t gbase = (size_t)grp * 16 * 512;
  const size_t coff = gbase + (size_t)fr * 512 + w * 64 + fq * 4;  // consumer
  const size_t poff = gbase + (size_t)b * 512 + slot * 16 + (cc >> 1); // producer pair
  const f32x4 zero = {0.f, 0.f, 0.f, 0.f};

  float pxr, pxz, pxe, pxh, ptm;
  {
    const _Float16* xp = xgh + (size_t)gm * 4096;
    pxr = (float)xp[gc]; pxz = (float)xp[1024 + gc];
    pxe = (float)xp[2048 + gc]; pxh = (float)xp[3072 + gc];
    ptm = tanh_(ms[(size_t)gm * 1024 + gc]);
  }

  int trust = 1, streak = 0;

  #pragma clang loop unroll(disable)
  for (int t = 0; t < TSTEPS; t++) {
    // ======== phase A: h(t) -> gates; publish rh (tag t+1)
    half8 av[4];
    if (t == 0) {
      const float* hp = h0 + (size_t)(grp * 16 + fr) * 1024 + w * 128 + fq * 8;
      #pragma unroll
      for (int ks = 0; ks < 4; ks++) {
        float4v a = *(const float4v*)(hp + ks * 32);
        float4v c = *(const float4v*)(hp + ks * 32 + 4);
        half8 h = { (_Float16)a.x, (_Float16)a.y, (_Float16)a.z, (_Float16)a.w,
                    (_Float16)c.x, (_Float16)c.y, (_Float16)c.z, (_Float16)c.w };
        av[ks] = h;
      }
    } else {
      unsigned tg = (ep16 << 16) | (unsigned)t;
      int esc = consume_frag<LOCAL>(hxF + coff, hxD + coff, hLB, hDB, tg, av, trust);
      if (LOCAL) { if (esc) { if (++streak > 6) trust = 0; } else streak = 0; }
    }
    f32x4 accA[6];
    #pragma unroll
    for (int nt = 0; nt < 6; nt++) accA[nt] = zero;
    #pragma unroll
    for (int ks = 0; ks < 4; ks++)
      #pragma unroll
      for (int nt = 0; nt < 6; nt++)
        accA[nt] = MFMA(av[ks], wA[nt][ks], accA[nt]);
    #pragma unroll
    for (int nt = 0; nt < 6; nt++)
      #pragma unroll
      for (int r = 0; r < 4; r++)
        red[(w * 6 + nt) * TP + (fq * 4 + r) * RP + fr] = accA[nt][r];
    __syncthreads();                              // S1
    float sr = pxr + bhr, sz = pxz + bhz, se = pxe + bhe;
    {
      const int boff = b * RP + (cc & 15) + (cc >> 4) * TP;
      #pragma unroll
      for (int w8 = 0; w8 < 8; w8++) {
        const float* rp = red + w8 * 6 * TP + boff;
        sr += rp[0]; sz += rp[2 * TP]; se += rp[4 * TP];
      }
    }
    float rg = sigm(sr);
    float zz = sigm(sz), ee = sigm(se);
    {
      unsigned tg = (ep16 << 16) | (unsigned)(t + 1);
      float rv = rg * hreg;
      unsigned us = (unsigned)(unsigned short)__builtin_bit_cast(unsigned short, (_Float16)rv);
      unsigned v01 = us | (((unsigned)__shfl_down((int)us, 1) & 0xFFFFu) << 16);
      unsigned v23 = (unsigned)__shfl_down((int)v01, 2);
      if (!(cc & 3)) {
        if (LOCAL) {
          i32x4 pkt = { (int)v01, (int)tg, (int)v23, (int)tg };
          *(i32x4*)(rhxF + poff) = pkt;           // plain 16B store -> local L2
        }
      }
      asm volatile("s_waitcnt vmcnt(0)" ::: "memory");
      __syncthreads();                            // S2: L2 data visible (+red guard)
      if (LOCAL && tid == 0) hLA[slot] = tg;      // L2 hint (plain store)
      if (!(cc & 3)) {                            // MALL dups (fire-and-forget)
        ast64(rhxD + poff,     ((u64)tg << 32) | (u64)v01);
        ast64(rhxD + poff + 1, ((u64)tg << 32) | (u64)v23);
      }
      if (!LOCAL) {
        __syncthreads();
        if (tid == 0) ast(hDA + slot, tg);
      }
    }
    float nxr = 0, nxz = 0, nxe = 0, nxh = 0, ntm = 0;
    if (t + 1 < TSTEPS) {
      const _Float16* xp = xgh + (size_t)((t + 1) * 64 + gm) * 4096;
      nxr = (float)xp[gc]; nxz = (float)xp[1024 + gc];
      nxe = (float)xp[2048 + gc]; nxh = (float)xp[3072 + gc];
      ntm = tanh_(ms[(size_t)(t + 1) * 65536 + gm * 1024 + gc]);
    }

    // ======== phase B: rh(t) -> hhat; h update; publish h(t+1)
    half8 bv[4];
    {
      unsigned tg = (ep16 << 16) | (unsigned)(t + 1);
      int esc = consume_frag<LOCAL>(rhxF + coff, rhxD + coff, hLA, hDA, tg, bv, trust);
      if (LOCAL) { if (esc) { if (++streak > 6) trust = 0; } else streak = 0; }
    }
    f32x4 accB[2];
    #pragma unroll
    for (int nt = 0; nt < 2; nt++) accB[nt] = zero;
    #pragma unroll
    for (int ks = 0; ks < 4; ks++)
      #pragma unroll
      for (int nt = 0; nt < 2; nt++)
        accB[nt] = MFMA(bv[ks], wB[nt][ks], accB[nt]);
    #pragma unroll
    for (int nt = 0; nt < 2; nt++)
      #pragma unroll
      for (int r = 0; r < 4; r++)
        red[(w * 6 + nt) * TP + (fq * 4 + r) * RP + fr] = accB[nt][r];
    __syncthreads();                              // S3
    float s = pxh + brr;
    {
      const int boff = b * RP + (cc & 15) + (cc >> 4) * TP;
      #pragma unroll
      for (int w8 = 0; w8 < 8; w8++) s += red[w8 * 6 * TP + boff];
    }
    float hh = tanh_(s);
    float hn = zz * hreg + (1.f - zz) * hh + ee * ptm;
    hreg = hn;
    {
      unsigned tg = (ep16 << 16) | (unsigned)(t + 1);
      unsigned us = (unsigned)(unsigned short)__builtin_bit_cast(unsigned short, (_Float16)hn);
      unsigned v01 = us | (((unsigned)__shfl_down((int)us, 1) & 0xFFFFu) << 16);
      unsigned v23 = (unsigned)__shfl_down((int)v01, 2);
      if (!(cc & 3)) {
        if (LOCAL) {
          i32x4 pkt = { (int)v01, (int)tg, (int)v23, (int)tg };
          *(i32x4*)(hxF + poff) = pkt;
        }
      }
      asm volatile("s_waitcnt vmcnt(0)" ::: "memory");
      __syncthreads();                            // S4
      if (LOCAL && tid == 0) hLB[slot] = tg;
      if (!(cc & 3)) {
        ast64(hxD + poff,     ((u64)tg << 32) | (u64)v01);
        ast64(hxD + poff + 1, ((u64)tg << 32) | (u64)v23);
      }
      if (!LOCAL) {
        __syncthreads();
        if (tid == 0) ast(hDB + slot, tg);
      }
    }
    __builtin_nontemporal_store(hn, out + (size_t)t * 65536 + gm * 1024 + gc);
    pxr = nxr; pxz = nxz; pxe = nxe; pxh = nxh; ptm = ntm;
  }
  out[(size_t)TSTEPS * 65536 + gm * 1024 + gc] = hreg;
}

__global__ __launch_bounds__(512, 2) void krec(
    const _Float16* __restrict__ xgh, const float* __restrict__ ms,
    const _Float16* __restrict__ whh, const _Float16* __restrict__ wr,
    const float* __restrict__ b_hh, const float* __restrict__ b_r,
    const float* __restrict__ h0,
    u64* __restrict__ hxF, u64* __restrict__ rhxF,
    u64* __restrict__ hxD, u64* __restrict__ rhxD,
    float* __restrict__ out, unsigned* __restrict__ ctrM,
    unsigned* __restrict__ pers) {
  __shared__ float red[48 * TP];
  __shared__ int sh[3];
  const int tid = threadIdx.x;
  unsigned* reg = ctrM;                 // [0..7] XCD census, [8] barrier (memset)
  unsigned* epoch = pers;               // NOT memset: monotonic across replays
  unsigned* hintL = pers + 64;          // L2 hint lines (persistent, epoch-tagged)
  unsigned* hintD = pers + 64 + 256;    // MALL hint lines (fallback)

  if (tid == 0) {
    if (blockIdx.x == 0) (void)aadd(epoch);       // once per launch, pre-census
    unsigned x;
    asm volatile("s_getreg_b32 %0, hwreg(HW_REG_XCC_ID)" : "=s"(x));
    x &= 7u;
    unsigned slot = aadd(&reg[x]);
    asm volatile("s_waitcnt vmcnt(0)" ::: "memory");
    aadd(&reg[8]);
    unsigned cnt = 0;
    for (long it = 0; it < 4000000; ++it) {
      cnt = ald(&reg[8]);
      if (cnt >= 256u) break;
      __builtin_amdgcn_s_sleep(8);
    }
    int ok = (cnt >= 256u);
    if (ok)
      #pragma unroll
      for (int i = 0; i < 8; i++) ok &= (ald(&reg[i]) == 32u);
    sh[0] = ok; sh[1] = (int)(x * 32u + (slot & 31u));
    sh[2] = (int)(ald(epoch) & 0xFFFFu);
  }
  __syncthreads();
  const unsigned ep16 = (unsigned)sh[2];

  if (sh[0]) {
    const int grp = sh[1] >> 5, slot = sh[1] & 31;
    if (grp >= 4) return;                         // XCDs 4-7 idle in LOCAL mode
    run_rec<1>(tid, grp, slot, ep16, xgh, ms, whh, wr, b_hh, b_r, h0,
               hxF, rhxF, hxD, rhxD, hintL, hintD, out, red);
  } else {
    const int bid = (int)blockIdx.x;
    if (bid >= 128) return;
    run_rec<0>(tid, bid >> 5, bid & 31, ep16, xgh, ms, whh, wr, b_hh, b_r, h0,
               hxF, rhxF, hxD, rhxD, hintL, hintD, out, red);
  }
}

extern "C" void kernel_launch(void* const* d_in, const int* in_sizes, int n_in,
                              void* d_out, int out_size, void* d_ws, size_t ws_size,
                              hipStream_t stream) {
  const float* xs   = (const float*)d_in[0];
  const float* ms   = (const float*)d_in[1];
  const float* h0   = (const float*)d_in[2];
  const float* W_ih = (const float*)d_in[3];
  const float* b_ih = (const float*)d_in[4];
  const float* W_hh = (const float*)d_in[5];
  const float* b_hh = (const float*)d_in[6];
  const float* W_xh = (const float*)d_in[7];
  const float* b_xh = (const float*)d_in[8];
  const float* W_r  = (const float*)d_in[9];
  const float* b_r  = (const float*)d_in[10];

  char* ws = (char*)d_ws;
  size_t off = 0;
  _Float16* xs_h = (_Float16*)(ws + off); off += 67108864;   // [32768][1024] f16
  _Float16* wcat = (_Float16*)(ws + off); off += 8388608;    // [4096][1024] f16
  _Float16* whh  = (_Float16*)(ws + off); off += 6291456;    // [3072][1024] f16
  _Float16* wr   = (_Float16*)(ws + off); off += 2097152;    // [1024][1024] f16
  _Float16* xgh  = (_Float16*)(ws + off); off += 268435456;  // [32768][4096] f16
  u64* hxF  = (u64*)(ws + off); off += 262144;  // L2 fast msgs [4grp][16r][512]
  u64* rhxF = (u64*)(ws + off); off += 262144;
  u64* hxD  = (u64*)(ws + off); off += 262144;  // MALL dup msgs (same layout)
  u64* rhxD = (u64*)(ws + off); off += 262144;
  unsigned* ctrM = (unsigned*)(ws + off); off += 256;   // census (memset each launch)
  unsigned* pers = (unsigned*)(ws + off); off += 4096;  // epoch + hints (NOT memset)

  hipMemsetAsync(ctrM, 0, 256, stream);
  kconv<<<2048, 256, 0, stream>>>(xs, W_ih, W_xh, W_hh, W_r,
                                  xs_h, wcat, whh, wr);
  kgemm<<<dim3(32, 256), 256, 0, stream>>>(xs_h, wcat, b_ih, b_xh, xgh);
  krec<<<256, 512, 0, stream>>>(xgh, ms, whh, wr, b_hh, b_r, h0,
                                hxF, rhxF, hxD, rhxD, (float*)d_out, ctrM, pers);
}

// Round 12
// 4317.193 us; speedup vs baseline: 7.3791x; 7.3791x over previous
//
#include <hip/hip_runtime.h>
#include <stdint.h>

#define TSTEPS 512

typedef __attribute__((ext_vector_type(8))) _Float16 half8;
typedef __attribute__((ext_vector_type(4))) _Float16 half4;
typedef __attribute__((ext_vector_type(4))) float f32x4;
typedef __attribute__((ext_vector_type(4))) float float4v;
typedef unsigned long long u64;

static __device__ __forceinline__ float sigm(float x) { return 1.f / (1.f + __expf(-x)); }
static __device__ __forceinline__ float tanh_(float x) {
  x = fminf(15.f, fmaxf(-15.f, x));
  float e = __expf(-2.f * x);
  return (1.f - e) / (1.f + e);
}
static __device__ __forceinline__ half8 ld8(const _Float16* p) { return *(const half8*)p; }
static __device__ __forceinline__ f32x4 MFMA(half8 a, half8 b, f32x4 c) {
  return __builtin_amdgcn_mfma_f32_16x16x32_f16(a, b, c, 0, 0, 0);
}

// ---- MALL primitives (agent scope; proven r4/r5/r8) ----
static __device__ __forceinline__ unsigned aadd(unsigned* p) {
  return __hip_atomic_fetch_add(p, 1u, __ATOMIC_RELAXED, __HIP_MEMORY_SCOPE_AGENT);
}
static __device__ __forceinline__ unsigned ald(const unsigned* p) {
  return __hip_atomic_load(p, __ATOMIC_RELAXED, __HIP_MEMORY_SCOPE_AGENT);
}
static __device__ __forceinline__ void ast(unsigned* p, unsigned v) {
  __hip_atomic_store(p, v, __ATOMIC_RELAXED, __HIP_MEMORY_SCOPE_AGENT);
}
struct U64x2 { u64 x, y; };
static __device__ __forceinline__ half8 ld_msg16(const u64* p) {
  u64 a = __hip_atomic_load(p,     __ATOMIC_RELAXED, __HIP_MEMORY_SCOPE_AGENT);
  u64 b = __hip_atomic_load(p + 1, __ATOMIC_RELAXED, __HIP_MEMORY_SCOPE_AGENT);
  U64x2 u{a, b};
  return __builtin_bit_cast(half8, u);
}
static __device__ __forceinline__ void st_msg(u64* p, u64 v) {
  __hip_atomic_store(p, v, __ATOMIC_RELAXED, __HIP_MEMORY_SCOPE_AGENT);
}
static __device__ __forceinline__ void wait_flags(const unsigned* line, unsigned tag) {
  const unsigned* p = line + (threadIdx.x & 31);
  while (!__all(ald(p) >= tag))
    __builtin_amdgcn_s_sleep(1);
  asm volatile("" ::: "memory");
}
static __device__ __forceinline__ void wait_blk(const unsigned* r) {
  while (ald(r) < 32u) __builtin_amdgcn_s_sleep(4);
  asm volatile("" ::: "memory");
}
// f16 write-through to MALL (cross-XCD visible without dirty-L2 hazard)
static __device__ __forceinline__ void st_f16_wt(_Float16* p, float v) {
  unsigned u = (unsigned)(unsigned short)__builtin_bit_cast(unsigned short, (_Float16)v);
  asm volatile("global_store_short %0, %1, off sc0 sc1" :: "v"(p), "v"(u) : "memory");
}

// ---------------- f32 -> f16 conversion / init (r8-identical) ----------------
__global__ __launch_bounds__(256) void kconv(
    const float* __restrict__ xs, const float* __restrict__ wih,
    const float* __restrict__ wxh, const float* __restrict__ whhf,
    const float* __restrict__ wrf, const float* __restrict__ h0,
    _Float16* __restrict__ xs_h, _Float16* __restrict__ wcat,
    _Float16* __restrict__ whh, _Float16* __restrict__ wr,
    _Float16* __restrict__ hx) {
  const long n1 = 8388608;   // xs / 4
  const long n2 = 1048576;   // wcat / 4
  const long n3 = 786432;    // whh / 4
  const long n4 = 262144;    // wr / 4
  const long n5 = 16384;     // h0 / 4 -> hx parity-0
  const long total = n1 + n2 + n3 + n4 + n5;
  for (long i = (long)blockIdx.x * 256 + threadIdx.x; i < total; i += (long)gridDim.x * 256) {
    const float* s; _Float16* d;
    if (i < n1) { s = xs + i * 4; d = xs_h + i * 4; }
    else if (i < n1 + n2) {
      long e = (i - n1) * 4;
      s = (e < 3145728) ? (wih + e) : (wxh + (e - 3145728));
      d = wcat + e;
    } else if (i < n1 + n2 + n3) { long e = (i - n1 - n2) * 4; s = whhf + e; d = whh + e; }
    else if (i < n1 + n2 + n3 + n4) { long e = (i - n1 - n2 - n3) * 4; s = wrf + e; d = wr + e; }
    else { long e = (i - n1 - n2 - n3 - n4) * 4; s = h0 + e; d = hx + e; }
    float4v v = *(const float4v*)s;
    half4 o = { (_Float16)v.x, (_Float16)v.y, (_Float16)v.z, (_Float16)v.w };
    *(half4*)d = o;
  }
}

// ---------------- gemm half: 8192 tiles (128x128), bm-major, ready counters ----------------
static __device__ void run_gemm(
    int tid, int gw,
    const _Float16* __restrict__ X, const _Float16* __restrict__ W,
    const float* __restrict__ b_ih, const float* __restrict__ b_xh,
    _Float16* __restrict__ C, unsigned* __restrict__ ready,
    _Float16* As, _Float16* Bs) {
  const int half = tid >> 8;         // two independent 256-thread tile engines
  const int htid = tid & 255;
  const int lane = htid & 63;
  const int w4 = htid >> 6;
  const int wm = (w4 >> 1) * 64, wn = (w4 & 1) * 64;
  const int arow = htid >> 2;
  const int kk8 = (htid & 3) * 8;
  const int fr = lane & 15, fq = lane >> 4;
  _Float16* as = As + half * 5120;
  _Float16* bs = Bs + half * 5120;
  const f32x4 zero = {0.f, 0.f, 0.f, 0.f};

  for (int i = 0; i < 32; ++i) {
    const int j = gw * 2 + half + 256 * i;   // bm-major job order
    const int bm = j >> 5, bn = j & 31;
    const int rb = bm * 128, cb = bn * 128;
    f32x4 acc[4][4];
    #pragma unroll
    for (int a = 0; a < 4; a++)
      #pragma unroll
      for (int b = 0; b < 4; b++) acc[a][b] = zero;
    for (int kt = 0; kt < 1024; kt += 32) {
      __syncthreads();
      #pragma unroll
      for (int jj = 0; jj < 2; jj++) {
        int r = jj * 64 + arow;
        *(half8*)(as + r * 40 + kk8) = ld8(X + (size_t)(rb + r) * 1024 + kt + kk8);
        *(half8*)(bs + r * 40 + kk8) = ld8(W + (size_t)(cb + r) * 1024 + kt + kk8);
      }
      __syncthreads();
      half8 af[4], bfr[4];
      #pragma unroll
      for (int q = 0; q < 4; q++) {
        af[q]  = *(const half8*)(as + (wm + q * 16 + fr) * 40 + fq * 8);
        bfr[q] = *(const half8*)(bs + (wn + q * 16 + fr) * 40 + fq * 8);
      }
      #pragma unroll
      for (int mi = 0; mi < 4; mi++)
        #pragma unroll
        for (int ni = 0; ni < 4; ni++)
          acc[mi][ni] = MFMA(af[mi], bfr[ni], acc[mi][ni]);
    }
    #pragma unroll
    for (int mi = 0; mi < 4; mi++)
      #pragma unroll
      for (int ni = 0; ni < 4; ni++) {
        int col = cb + wn + ni * 16 + fr;
        float bias = (col < 3072) ? b_ih[col] : b_xh[col - 3072];
        #pragma unroll
        for (int r = 0; r < 4; r++) {
          int row = rb + wm + mi * 16 + fq * 4 + r;
          st_f16_wt(C + (size_t)row * 4096 + col, acc[mi][ni][r] + bias);
        }
      }
    asm volatile("s_waitcnt vmcnt(0)" ::: "memory");   // C at MALL
    __syncthreads();
    if (htid == 0) (void)aadd(&ready[bm]);
  }
}

// ---------------- rec half: r8-proven protocol + xg ready-gating ----------------
#define RP 20
#define TP (16 * RP)

static __device__ void run_rec(
    int tid, int bid,
    const _Float16* __restrict__ xgh, const float* __restrict__ ms,
    const _Float16* __restrict__ whh, const _Float16* __restrict__ wr,
    const float* __restrict__ b_hh, const float* __restrict__ b_r,
    const float* __restrict__ h0,
    u64* __restrict__ hmsg, u64* __restrict__ rhmsg,
    float* __restrict__ out, unsigned* __restrict__ ctr,
    unsigned* __restrict__ ready, float* red) {
  const int lane = tid & 63, w = tid >> 6;
  const int fr = lane & 15, fq = lane >> 4;
  const int g = bid >> 5;
  const int slot = bid & 31;
  const int colbase = slot * 32;
  unsigned* flagA = ctr + (g * 2 + 0) * 32;   // rh(t) published => t+1
  unsigned* flagB = ctr + (g * 2 + 1) * 32;   // h(t) published  => t

  // weight fragments -> registers (unified VGPR/AGPR file keeps them resident)
  half8 wA[6][4], wB[2][4];
  #pragma unroll
  for (int nt = 0; nt < 6; nt++)
    #pragma unroll
    for (int ks = 0; ks < 4; ks++)
      wA[nt][ks] = ld8(whh + (size_t)((nt >> 1) * 1024 + colbase + (nt & 1) * 16 + fr) * 1024
                            + w * 128 + ks * 32 + fq * 8);
  #pragma unroll
  for (int nt = 0; nt < 2; nt++)
    #pragma unroll
    for (int ks = 0; ks < 4; ks++)
      wB[nt][ks] = ld8(wr + (size_t)(colbase + nt * 16 + fr) * 1024
                           + w * 128 + ks * 32 + fq * 8);

  const int b = tid >> 5, cc = tid & 31;
  const int gc = colbase + cc;
  const int gm = g * 16 + b;
  const float bhr = b_hh[gc], bhz = b_hh[1024 + gc], bhe = b_hh[2048 + gc];
  const float brr = b_r[gc];
  float hreg = h0[(size_t)gm * 1024 + gc];

  const u64* hcons = hmsg  + (g * 16 + fr) * 256 + w * 32 + fq * 2;
  const u64* rcons = rhmsg + (g * 16 + fr) * 256 + w * 32 + fq * 2;
  u64* hprod = hmsg  + gm * 256 + (gc >> 2);
  u64* rprod = rhmsg + gm * 256 + (gc >> 2);

  const f32x4 zero = {0.f, 0.f, 0.f, 0.f};

  // gated initial prefetch (needs xgh block 0)
  float pxr, pxz, pxe, pxh, ptm;
  wait_blk(&ready[0]);
  {
    const _Float16* xp = xgh + (size_t)gm * 4096;
    pxr = (float)xp[gc]; pxz = (float)xp[1024 + gc];
    pxe = (float)xp[2048 + gc]; pxh = (float)xp[3072 + gc];
    ptm = tanh_(ms[(size_t)gm * 1024 + gc]);
  }

  #pragma clang loop unroll(disable)
  for (int t = 0; t < TSTEPS; t++) {
    const int ph = t & 1;
    // ======== phase A: h(t) -> gates; publish rh(t)
    wait_flags(flagB, (unsigned)t);
    half8 av[4];
    #pragma unroll
    for (int ks = 0; ks < 4; ks++)
      av[ks] = ld_msg16(hcons + ph * 16384 + ks * 8);
    f32x4 accA[6];
    #pragma unroll
    for (int nt = 0; nt < 6; nt++) accA[nt] = zero;
    #pragma unroll
    for (int ks = 0; ks < 4; ks++)
      #pragma unroll
      for (int nt = 0; nt < 6; nt++)
        accA[nt] = MFMA(av[ks], wA[nt][ks], accA[nt]);
    #pragma unroll
    for (int nt = 0; nt < 6; nt++)
      #pragma unroll
      for (int r = 0; r < 4; r++)
        red[(w * 6 + nt) * TP + (fq * 4 + r) * RP + fr] = accA[nt][r];
    __syncthreads();                            // S1
    float sr = pxr + bhr, sz = pxz + bhz, se = pxe + bhe;
    {
      const int boff = b * RP + (cc & 15) + (cc >> 4) * TP;
      #pragma unroll
      for (int w8 = 0; w8 < 8; w8++) {
        const float* rp = red + w8 * 6 * TP + boff;
        sr += rp[0]; sz += rp[2 * TP]; se += rp[4 * TP];
      }
    }
    float rg = sigm(sr);
    float zz = sigm(sz), ee = sigm(se);
    {
      float rv = rg * hreg;
      unsigned us = (unsigned)(unsigned short)__builtin_bit_cast(unsigned short, (_Float16)rv);
      unsigned v01 = us | (((unsigned)__shfl_down((int)us, 1) & 0xFFFFu) << 16);
      unsigned v23 = (unsigned)__shfl_down((int)v01, 2);
      if (!(cc & 3))
        st_msg(rprod + ph * 16384, ((u64)v23 << 32) | (u64)v01);
    }
    asm volatile("s_waitcnt vmcnt(0)" ::: "memory");
    __syncthreads();                            // S2: rh acked (+red guard)
    if (tid == 0)
      ast(flagA + slot, (unsigned)(t + 1));
    // overlap window: gated prefetch of next step's xg/ms
    float nxr = 0.f, nxz = 0.f, nxe = 0.f, nxh = 0.f, ntm = 0.f;
    if (t + 1 < TSTEPS) {
      wait_blk(&ready[(t + 1) >> 1]);
      const _Float16* xp = xgh + (size_t)((t + 1) * 64 + gm) * 4096;
      nxr = (float)xp[gc]; nxz = (float)xp[1024 + gc];
      nxe = (float)xp[2048 + gc]; nxh = (float)xp[3072 + gc];
      ntm = tanh_(ms[(size_t)(t + 1) * 65536 + gm * 1024 + gc]);
    }
    wait_flags(flagA, (unsigned)(t + 1));

    // ======== phase B: rh(t) -> hhat; h update; publish h(t+1)
    half8 bv[4];
    #pragma unroll
    for (int ks = 0; ks < 4; ks++)
      bv[ks] = ld_msg16(rcons + ph * 16384 + ks * 8);
    f32x4 accB[2];
    #pragma unroll
    for (int nt = 0; nt < 2; nt++) accB[nt] = zero;
    #pragma unroll
    for (int ks = 0; ks < 4; ks++)
      #pragma unroll
      for (int nt = 0; nt < 2; nt++)
        accB[nt] = MFMA(bv[ks], wB[nt][ks], accB[nt]);
    #pragma unroll
    for (int nt = 0; nt < 2; nt++)
      #pragma unroll
      for (int r = 0; r < 4; r++)
        red[(w * 6 + nt) * TP + (fq * 4 + r) * RP + fr] = accB[nt][r];
    __syncthreads();                            // S3
    float s = pxh + brr;
    {
      const int boff = b * RP + (cc & 15) + (cc >> 4) * TP;
      #pragma unroll
      for (int w8 = 0; w8 < 8; w8++) s += red[w8 * 6 * TP + boff];
    }
    float hh = tanh_(s);
    float hn = zz * hreg + (1.f - zz) * hh + ee * ptm;
    hreg = hn;
    {
      unsigned us = (unsigned)(unsigned short)__builtin_bit_cast(unsigned short, (_Float16)hn);
      unsigned v01 = us | (((unsigned)__shfl_down((int)us, 1) & 0xFFFFu) << 16);
      unsigned v23 = (unsigned)__shfl_down((int)v01, 2);
      if (!(cc & 3))
        st_msg(hprod + (ph ^ 1) * 16384, ((u64)v23 << 32) | (u64)v01);
    }
    asm volatile("s_waitcnt vmcnt(0)" ::: "memory");
    __syncthreads();                            // S4: h acked (+red guard)
    if (tid == 0)
      ast(flagB + slot, (unsigned)(t + 1));
    __builtin_nontemporal_store(hn, out + (size_t)t * 65536 + gm * 1024 + gc);
    pxr = nxr; pxz = nxz; pxe = nxe; pxh = nxh; ptm = ntm;
  }
  out[(size_t)TSTEPS * 65536 + gm * 1024 + gc] = hreg;
}

// ---------------- fused kernel: 128 rec wgs + 128 gemm wgs ----------------
__global__ __launch_bounds__(512, 2) void krec(
    const _Float16* __restrict__ xgh_c, const float* __restrict__ ms,
    const _Float16* __restrict__ whh, const _Float16* __restrict__ wr,
    const float* __restrict__ b_hh, const float* __restrict__ b_r,
    const float* __restrict__ h0,
    u64* __restrict__ hmsg, u64* __restrict__ rhmsg,
    float* __restrict__ out, unsigned* __restrict__ ctr,
    const _Float16* __restrict__ X, const _Float16* __restrict__ W,
    const float* __restrict__ b_ih, const float* __restrict__ b_xh,
    _Float16* __restrict__ xgh_w) {
  __shared__ float red[48 * TP];                 // 60 KiB (rec)
  __shared__ _Float16 As[2 * 5120], Bs[2 * 5120]; // 40 KiB (gemm)
  const int tid = threadIdx.x;
  const int bid = (int)blockIdx.x;
  unsigned* ready = ctr + 256;                   // per-bm-block counters

  if (bid < 128) {
    run_rec(tid, bid, xgh_c, ms, whh, wr, b_hh, b_r, h0,
            hmsg, rhmsg, out, ctr, ready, red);
  } else {
    run_gemm(tid, bid - 128, X, W, b_ih, b_xh, xgh_w, ready, As, Bs);
  }
}

extern "C" void kernel_launch(void* const* d_in, const int* in_sizes, int n_in,
                              void* d_out, int out_size, void* d_ws, size_t ws_size,
                              hipStream_t stream) {
  const float* xs   = (const float*)d_in[0];
  const float* ms   = (const float*)d_in[1];
  const float* h0   = (const float*)d_in[2];
  const float* W_ih = (const float*)d_in[3];
  const float* b_ih = (const float*)d_in[4];
  const float* W_hh = (const float*)d_in[5];
  const float* b_hh = (const float*)d_in[6];
  const float* W_xh = (const float*)d_in[7];
  const float* b_xh = (const float*)d_in[8];
  const float* W_r  = (const float*)d_in[9];
  const float* b_r  = (const float*)d_in[10];

  char* ws = (char*)d_ws;
  size_t off = 0;
  _Float16* xs_h = (_Float16*)(ws + off); off += 67108864;   // [32768][1024] f16
  _Float16* wcat = (_Float16*)(ws + off); off += 8388608;    // [4096][1024] f16
  _Float16* whh  = (_Float16*)(ws + off); off += 6291456;    // [3072][1024] f16
  _Float16* wr   = (_Float16*)(ws + off); off += 2097152;    // [1024][1024] f16
  _Float16* xgh  = (_Float16*)(ws + off); off += 268435456;  // [32768][4096] f16
  _Float16* hx   = (_Float16*)(ws + off); off += 262144;     // [2][64][1024] f16 parity dbuf
  _Float16* rhx  = (_Float16*)(ws + off); off += 262144;     // [2][64][1024] f16 parity dbuf
  unsigned* ctr  = (unsigned*)(ws + off); off += 2048;       // 256 flags + 256 ready

  hipMemsetAsync(ctr, 0, 2048, stream);
  kconv<<<2048, 256, 0, stream>>>(xs, W_ih, W_xh, W_hh, W_r, h0,
                                  xs_h, wcat, whh, wr, hx);
  krec<<<256, 512, 0, stream>>>(xgh, ms, whh, wr, b_hh, b_r, h0,
                                (u64*)hx, (u64*)rhx, (float*)d_out, ctr,
                                xs_h, wcat, b_ih, b_xh, xgh);
}